// Round 14
// baseline (2515.333 us; speedup 1.0000x reference)
//
#include <hip/hip_runtime.h>
#include <math.h>

#define E 512
#define V 50257
#define T 1024
#define B 4
#define H 8
#define HS 64
#define L 4
#define FF 2048
#define NTOK 4096   // B*T

#define NPAD 50304  // 393*128, padded V for MFMA tiles
#define KSPL 1024   // split row length for K=512: [hi(512) | lo(512)]

typedef _Float16 f16;
typedef _Float16 f16x8 __attribute__((ext_vector_type(8)));
typedef float    f32x4 __attribute__((ext_vector_type(4)));
typedef float    f32x16 __attribute__((ext_vector_type(16)));

__device__ inline float wave_max(float v){ for(int o=32;o;o>>=1) v=fmaxf(v,__shfl_xor(v,o)); return v; }
__device__ inline float wave_sum(float v){ for(int o=32;o;o>>=1) v+=__shfl_xor(v,o); return v; }

// online-LSE merge with -inf guard
__device__ inline void lse_merge(float& m, float& s, float m2, float s2){
  float mn = fmaxf(m, m2);
  if (mn == -INFINITY){ m = mn; s = 0.f; return; }
  s = s*__expf(m - mn) + s2*__expf(m2 - mn);
  m = mn;
}

// ---------------- embedding fused with ln1 + split-fp16 output ----------------
__global__ __launch_bounds__(256) void embed_ln_split_kernel(const int* __restrict__ idx,
    const float* __restrict__ tok, const float* __restrict__ pos,
    const float* __restrict__ g, const float* __restrict__ bb,
    float* __restrict__ X, f16* __restrict__ A2){
  int row = blockIdx.x; int tid = threadIdx.x;
  int t = row & (T-1);
  const float* te = tok + (size_t)idx[row]*E;
  const float* pe = pos + (size_t)t*E;
  float v0 = te[tid] + pe[tid];
  float v1 = te[tid+256] + pe[tid+256];
  float* xr = X + (size_t)row*E;
  xr[tid] = v0; xr[tid+256] = v1;
  int wave = tid>>6, lane = tid&63;
  __shared__ float r1[4], r2[4];
  float s = wave_sum(v0+v1);
  if (!lane) r1[wave]=s;
  __syncthreads();
  float mean = (r1[0]+r1[1]+r1[2]+r1[3]) * (1.f/E);
  float d0=v0-mean, d1=v1-mean;
  float vs = wave_sum(d0*d0+d1*d1);
  if (!lane) r2[wave]=vs;
  __syncthreads();
  float var = (r2[0]+r2[1]+r2[2]+r2[3]) * (1.f/E);
  float rs = rsqrtf(var + 1e-5f);
  float y0 = d0*rs*g[tid]     + bb[tid];
  float y1 = d1*rs*g[tid+256] + bb[tid+256];
  size_t base = (size_t)row*KSPL;
  f16 h0=(f16)y0, h1=(f16)y1;
  A2[base + tid]         = h0;
  A2[base + E + tid]     = (f16)(y0 - (float)h0);
  A2[base + tid+256]     = h1;
  A2[base + E + tid+256] = (f16)(y1 - (float)h1);
}

// ---------------- reduce 4 partials + bias into X, fused with next LN + split-fp16 ----------------
__global__ __launch_bounds__(256) void red4_ln_split_kernel(const float* __restrict__ P,
    const float* __restrict__ bias, const float* __restrict__ g, const float* __restrict__ bb,
    float* __restrict__ X, f16* __restrict__ A2){
  int row = blockIdx.x; int tid = threadIdx.x;
  const size_t STRIDE = (size_t)NTOK*E;
  size_t i0 = (size_t)row*E + tid, i1 = i0 + 256;
  float v0 = X[i0] + P[i0] + P[i0+STRIDE] + P[i0+2*STRIDE] + P[i0+3*STRIDE] + bias[tid];
  float v1 = X[i1] + P[i1] + P[i1+STRIDE] + P[i1+2*STRIDE] + P[i1+3*STRIDE] + bias[tid+256];
  X[i0] = v0; X[i1] = v1;
  int wave = tid>>6, lane = tid&63;
  __shared__ float r1[4], r2[4];
  float s = wave_sum(v0+v1);
  if (!lane) r1[wave]=s;
  __syncthreads();
  float mean = (r1[0]+r1[1]+r1[2]+r1[3]) * (1.f/E);
  float d0=v0-mean, d1=v1-mean;
  float vs = wave_sum(d0*d0+d1*d1);
  if (!lane) r2[wave]=vs;
  __syncthreads();
  float var = (r2[0]+r2[1]+r2[2]+r2[3]) * (1.f/E);
  float rs = rsqrtf(var + 1e-5f);
  float y0 = d0*rs*g[tid]     + bb[tid];
  float y1 = d1*rs*g[tid+256] + bb[tid+256];
  size_t base = (size_t)row*KSPL;
  f16 h0=(f16)y0, h1=(f16)y1;
  A2[base + tid]         = h0;
  A2[base + E + tid]     = (f16)(y0 - (float)h0);
  A2[base + tid+256]     = h1;
  A2[base + E + tid+256] = (f16)(y1 - (float)h1);
}

// ---------------- layernorm (fp32 out, fallback path) ----------------
__global__ __launch_bounds__(256) void ln_kernel(const float* __restrict__ X,
    const float* __restrict__ g, const float* __restrict__ bb, float* __restrict__ O){
  int row = blockIdx.x; int tid = threadIdx.x;
  const float* x = X + (size_t)row*E;
  float v0 = x[tid], v1 = x[tid+256];
  int wave = tid>>6, lane = tid&63;
  __shared__ float r1[4], r2[4];
  float s = wave_sum(v0+v1);
  if (!lane) r1[wave]=s;
  __syncthreads();
  float mean = (r1[0]+r1[1]+r1[2]+r1[3]) * (1.f/E);
  float d0=v0-mean, d1=v1-mean;
  float vs = wave_sum(d0*d0+d1*d1);
  if (!lane) r2[wave]=vs;
  __syncthreads();
  float var = (r2[0]+r2[1]+r2[2]+r2[3]) * (1.f/E);
  float rs = rsqrtf(var + 1e-5f);
  float* o = O + (size_t)row*E;
  o[tid]     = d0*rs*g[tid]     + bb[tid];
  o[tid+256] = d1*rs*g[tid+256] + bb[tid+256];
}

// ---------------- tiled SGEMM (fp32 vector path, fallback only) ----------------
template<bool RELU, bool RESID>
__global__ __launch_bounds__(256) void sgemm(const float* __restrict__ A, const float* __restrict__ Bm,
    const float* __restrict__ bias, const float* __restrict__ Rs, float* __restrict__ C,
    int M, int N, int K, int Hn,
    long long sA, long long sB, long long sBias, long long sC){
  int z = blockIdx.z;
  A    += (long long)(z / Hn) * sA;
  Bm   += (long long)(z % Hn) * sB;
  bias += (long long)(z % Hn) * sBias;
  C    += (long long)z * sC;
  __shared__ float As[16][68];
  __shared__ float Bs[16][64];
  int tid = threadIdx.x;
  int tx = tid & 15, ty = tid >> 4;
  int m0 = blockIdx.y * 64, n0 = blockIdx.x * 64;
  int ar = tid >> 2, ac = (tid & 3) << 2;
  int br = tid >> 4, bc = (tid & 15) << 2;
  float acc[4][4] = {};
  const float* Ap = A + (size_t)(m0+ar)*K + ac;
  const float* Bp = Bm + (size_t)br*N + n0 + bc;
  int bn = n0 + bc;
  for (int k0=0; k0<K; k0+=16){
    float4 av = *(const float4*)Ap;
    As[ac+0][ar]=av.x; As[ac+1][ar]=av.y; As[ac+2][ar]=av.z; As[ac+3][ar]=av.w;
    float4 bv;
    if (bn+3 < N) bv = *(const float4*)Bp;
    else {
      bv.x = (bn+0<N)?Bp[0]:0.f; bv.y=(bn+1<N)?Bp[1]:0.f;
      bv.z = (bn+2<N)?Bp[2]:0.f; bv.w=(bn+3<N)?Bp[3]:0.f;
    }
    *(float4*)&Bs[br][bc] = bv;
    __syncthreads();
    #pragma unroll
    for (int kk=0; kk<16; ++kk){
      float4 a4 = *(const float4*)&As[kk][ty<<2];
      float4 b4 = *(const float4*)&Bs[kk][tx<<2];
      acc[0][0] = fmaf(a4.x,b4.x,acc[0][0]); acc[0][1] = fmaf(a4.x,b4.y,acc[0][1]);
      acc[0][2] = fmaf(a4.x,b4.z,acc[0][2]); acc[0][3] = fmaf(a4.x,b4.w,acc[0][3]);
      acc[1][0] = fmaf(a4.y,b4.x,acc[1][0]); acc[1][1] = fmaf(a4.y,b4.y,acc[1][1]);
      acc[1][2] = fmaf(a4.y,b4.z,acc[1][2]); acc[1][3] = fmaf(a4.y,b4.w,acc[1][3]);
      acc[2][0] = fmaf(a4.z,b4.x,acc[2][0]); acc[2][1] = fmaf(a4.z,b4.y,acc[2][1]);
      acc[2][2] = fmaf(a4.z,b4.z,acc[2][2]); acc[2][3] = fmaf(a4.z,b4.w,acc[2][3]);
      acc[3][0] = fmaf(a4.w,b4.x,acc[3][0]); acc[3][1] = fmaf(a4.w,b4.y,acc[3][1]);
      acc[3][2] = fmaf(a4.w,b4.z,acc[3][2]); acc[3][3] = fmaf(a4.w,b4.w,acc[3][3]);
    }
    __syncthreads();
    Ap += 16; Bp += (size_t)16*N;
  }
  #pragma unroll
  for (int i=0;i<4;++i){
    int row = m0 + (ty<<2) + i;
    float* crow = C + (size_t)row*N;
    #pragma unroll
    for (int j=0;j<4;++j){
      int col = n0 + (tx<<2) + j;
      if (col < N){
        float vv = acc[i][j] + bias[col];
        if (RESID) vv += Rs[(size_t)row*N + col];
        if (RELU)  vv = fmaxf(vv, 0.f);
        crow[col] = vv;
      }
    }
  }
}

// ================= fp16 A-split MFMA GEMM machinery =================
// C = Ahi*B + Alo*B  (A repr error ~2^-22; B fp16 rounding ~2^-11 rel)

#define GLOBAL_AS __attribute__((address_space(1)))
#define LDS_AS    __attribute__((address_space(3)))

__device__ inline void gll16(const void* g, void* l){
  __builtin_amdgcn_global_load_lds((const GLOBAL_AS void*)g, (LDS_AS void*)l, 16, 0, 0);
}

// transpose+convert, ALL LAYERS batched on z: W[z] [K][N] fp32 -> B1[z] [N][K] fp16
__global__ __launch_bounds__(256) void split_w_f16(const float* __restrict__ W,
    f16* __restrict__ B1, int N, int K){
  __shared__ float S[64][65];
  int n0 = blockIdx.x * 64;
  int k0 = blockIdx.y * 64;
  int lz = blockIdx.z;
  W  += (size_t)lz * ((size_t)K * N);
  B1 += (size_t)lz * ((size_t)N * K);
  int t = threadIdx.x;
  #pragma unroll
  for (int p=0;p<16;++p){
    int e = p*256 + t;
    int kl = e >> 6, nl = e & 63;
    S[kl][nl] = W[(size_t)(k0+kl)*N + n0+nl];
  }
  __syncthreads();
  #pragma unroll
  for (int p=0;p<16;++p){
    int e = p*256 + t;
    int nl = e >> 6, kl = e & 63;
    B1[(size_t)(n0+nl)*(size_t)K + (k0+kl)] = (f16)S[kl][nl];
  }
}

// fused qkv weights + bias concat, ALL LAYERS on z: -> B1[z] [1536][512], bqkv[z][1536]
__global__ __launch_bounds__(256) void split_wqkv_f16(const float* __restrict__ wq,
    const float* __restrict__ wk, const float* __restrict__ wv, f16* __restrict__ B1,
    const float* __restrict__ bq, const float* __restrict__ bk, const float* __restrict__ bv,
    float* __restrict__ bqkv){
  int lz = blockIdx.z;
  wq += (size_t)lz*H*E*HS; wk += (size_t)lz*H*E*HS; wv += (size_t)lz*H*E*HS;
  bq += (size_t)lz*H*HS;   bk += (size_t)lz*H*HS;   bv += (size_t)lz*H*HS;
  B1 += (size_t)lz*1536*512; bqkv += (size_t)lz*1536;
  if (blockIdx.x == 0 && blockIdx.y == 0){
    for (int i=threadIdx.x; i<1536; i+=256)
      bqkv[i] = (i < 512) ? bq[i] : (i < 1024 ? bk[i-512] : bv[i-1024]);
  }
  __shared__ float S[64][65];
  int n0 = blockIdx.x * 64;   // 24 tiles
  int e0 = blockIdx.y * 64;   // 8 tiles
  const float* W; int nloc;
  if (n0 < 512){ W = wq; nloc = n0; }
  else if (n0 < 1024){ W = wk; nloc = n0 - 512; }
  else { W = wv; nloc = n0 - 1024; }
  int h = nloc >> 6;
  int t = threadIdx.x;
  #pragma unroll
  for (int p=0;p<16;++p){
    int idx2 = p*256 + t;
    int e = idx2 >> 6, o = idx2 & 63;
    S[e][o] = W[((size_t)(h*E + e0 + e))*HS + o];
  }
  __syncthreads();
  #pragma unroll
  for (int p=0;p<16;++p){
    int idx2 = p*256 + t;
    int r = idx2 >> 6, c = idx2 & 63;
    B1[(size_t)(n0 + r)*512 + (e0 + c)] = (f16)S[c][r];
  }
}

// transpose+convert wf [E][V] -> B1 [NPAD][512] fp16, zero rows n>=V
__global__ __launch_bounds__(256) void split_bT_f16(const float* __restrict__ Wf, f16* __restrict__ B1){
  __shared__ float S[64][65];
  int n0 = blockIdx.x * 64;
  int k0 = blockIdx.y * 64;
  int t = threadIdx.x;
  #pragma unroll
  for (int p=0;p<16;++p){
    int e = p*256 + t;
    int kl = e >> 6, nl = e & 63;
    int n = n0 + nl;
    S[kl][nl] = (n < V) ? Wf[(size_t)(k0+kl)*V + n] : 0.f;
  }
  __syncthreads();
  #pragma unroll
  for (int p=0;p<16;++p){
    int e = p*256 + t;
    int nl = e >> 6, kl = e & 63;
    B1[(size_t)(n0+nl)*512 + (k0+kl)] = (f16)S[kl][nl];
  }
}

// fp16 MFMA GEMM: C[NTOK,NLOG] = A2[NTOK][2K](hi|lo fp16) x B1[Npad][K]^T (fp16)
// 128x128 tile, BK=64, 4 waves, 32x32x16 f16 MFMA (2x2 frags/wave, 4 k-phases of 16),
// XOR-swizzled LDS, global_load_lds staging. 2 passes (hi, lo) in-block.
// A/B frag: row=lane&31, k=(lane>>5)*8+j. C/D: col=lane&31, row=(reg&3)+8*(reg>>2)+4*(lane>>5).
// PARTIAL4: blockIdx.z = (term<<1)|khalf; raw partial -> C + z*NTOK*NLOG (bias in reduce).
template<bool RELU, bool OUTSPLIT, bool PARTIAL4, int K, int NLOG>
__global__ __launch_bounds__(256) void mfma_gemm_f16(
    const f16* __restrict__ A2, const f16* __restrict__ B1,
    const float* __restrict__ bias, float* __restrict__ C, f16* __restrict__ C2){
  __shared__ f16 As[128*64];
  __shared__ f16 Bs[128*64];
  int tid = threadIdx.x;
  int lane = tid & 63, wv = tid >> 6;
  int wm = wv >> 1, wn = wv & 1;
  int m0 = blockIdx.x * 128;
  int n0 = blockIdx.y * 128;

  f32x16 acc[2][2];
  #pragma unroll
  for (int i=0;i<2;++i)
    #pragma unroll
    for (int j=0;j<2;++j)
      #pragma unroll
      for (int r=0;r<16;++r) acc[i][j][r] = 0.f;

  constexpr size_t LDA = (size_t)(4*K);   // A row = 2K fp16
  constexpr size_t LDB = (size_t)(2*K);   // B row = K fp16
  const char* Abase = (const char*)A2 + (size_t)m0*LDA;
  const char* Bbase = (const char*)B1 + (size_t)n0*LDB;
  int halfm = wm*64, halfn = wn*64;

  constexpr int NPS = PARTIAL4 ? 1 : 2;
  constexpr int KRANGE = PARTIAL4 ? (K/2) : K;
  int kbase = PARTIAL4 ? ((int)blockIdx.z & 1)*(K/2) : 0;
  #pragma unroll
  for (int pi=0; pi<NPS; ++pi){
    int term = PARTIAL4 ? ((int)blockIdx.z >> 1) : pi;
    size_t abyte = ((size_t)term*K + (size_t)kbase)*2;
    size_t bbyte = (size_t)kbase*2;
    for (int kk=0; kk<KRANGE; kk+=64){
      const char* Ak = Abase + abyte + (size_t)kk*2;
      const char* Bk = Bbase + bbyte + (size_t)kk*2;
      #pragma unroll
      for (int p=0;p<4;++p){
        int slot = p*256 + tid;
        int row  = slot >> 3;
        int sch  = (slot & 7) ^ (row & 7);
        gll16(Ak + (size_t)row*LDA + (sch<<4), (char*)As + (p<<12) + (wv<<10));
      }
      #pragma unroll
      for (int p=0;p<4;++p){
        int slot = p*256 + tid;
        int row  = slot >> 3;
        int sch  = (slot & 7) ^ (row & 7);
        gll16(Bk + (size_t)row*LDB + (sch<<4), (char*)Bs + (p<<12) + (wv<<10));
      }
      __syncthreads();
      #pragma unroll
      for (int kp=0; kp<4; ++kp){            // 4 k-phases of 16
        f16x8 af[2], bfr[2];
        int chq = kp*2 + (lane >> 5);        // chunk = k-window*2 + lane-half
        #pragma unroll
        for (int mf=0; mf<2; ++mf){
          int r = halfm + mf*32 + (lane & 31);
          int sch = chq ^ (r & 7);
          af[mf] = *(const f16x8*)((const char*)As + r*128 + (sch<<4));
        }
        #pragma unroll
        for (int nf=0; nf<2; ++nf){
          int r = halfn + nf*32 + (lane & 31);
          int sch = chq ^ (r & 7);
          bfr[nf] = *(const f16x8*)((const char*)Bs + r*128 + (sch<<4));
        }
        #pragma unroll
        for (int mf=0; mf<2; ++mf)
          #pragma unroll
          for (int nf=0; nf<2; ++nf)
            acc[mf][nf] = __builtin_amdgcn_mfma_f32_32x32x16_f16(af[mf], bfr[nf], acc[mf][nf], 0, 0, 0);
      }
      __syncthreads();
    }
  }
  float* Cp = C;
  if (PARTIAL4) Cp += (size_t)blockIdx.z * ((size_t)NTOK*NLOG);
  #pragma unroll
  for (int mf=0; mf<2; ++mf){
    #pragma unroll
    for (int nf=0; nf<2; ++nf){
      int col = n0 + halfn + nf*32 + (lane & 31);
      if (col < NLOG){
        float bv = (PARTIAL4) ? 0.f : bias[col];
        #pragma unroll
        for (int reg=0; reg<16; ++reg){
          int row = m0 + halfm + mf*32 + (reg & 3) + 8*(reg >> 2) + 4*(lane >> 5);
          float vv = acc[mf][nf][reg];
          if (PARTIAL4){
            Cp[(size_t)row*NLOG + col] = vv;            // raw partial, bias in reduce
          } else if (OUTSPLIT){
            vv += bv;
            if (RELU) vv = fmaxf(vv, 0.f);
            f16 h = (f16)vv;
            C2[(size_t)row*(2*(size_t)NLOG) + col]        = h;
            C2[(size_t)row*(2*(size_t)NLOG) + NLOG + col] = (f16)(vv - (float)h);
          } else {
            vv += bv;
            if (RELU) vv = fmaxf(vv, 0.f);
            Cp[(size_t)row*NLOG + col] = vv;
          }
        }
      }
    }
  }
}

// ---------------- flash attention on fused QKV [B,T,1536]; writes split-fp16 output ----------------
// R11-proven: Q in registers (wave-uniform), aligned 68-float LDS rows, PV p via LDS b128 broadcast.
__global__ __launch_bounds__(256) void attn_fused_kernel(const float* __restrict__ QKV,
    const int* __restrict__ amask, f16* __restrict__ A2out){
  int blk = blockIdx.x;
  int qc = blk & 255;
  int bh = blk >> 8;
  int b = bh >> 3, h = bh & 7;
  int wave = threadIdx.x >> 6, lane = threadIdx.x & 63;
  int qi = (qc<<2) + wave;
  __shared__ float Ks[64][68];
  __shared__ float Vs[64][68];
  __shared__ float Ps[4][64];
  __shared__ int   Ms[64];
  const float* qrow = QKV + (size_t)(b*T + qi)*1536 + (h<<6);
  float4 qreg[16];
  #pragma unroll
  for (int d4=0; d4<16; ++d4) qreg[d4] = *(const float4*)(qrow + (d4<<2));
  const float* kb = QKV + (size_t)(b*T)*1536 + 512 + (h<<6);
  float acc=0.f, m=-INFINITY, l=0.f;
  int nchunk = (((qc<<2)+3)>>6) + 1;
  for (int c=0;c<nchunk;++c){
    __syncthreads();
    #pragma unroll
    for (int i=0;i<4;++i){
      int fi = threadIdx.x + i*256;
      int r = fi >> 4, f4 = fi & 15;
      const float* krow = kb + (size_t)(c*64 + r)*1536 + (f4<<2);
      float4 kv = *(const float4*)krow;
      float4 vv = *(const float4*)(krow + 512);
      int cc = f4 << 2;
      *(float4*)&Ks[r][cc] = kv;
      *(float4*)&Vs[r][cc] = vv;
    }
    if (threadIdx.x < 64) Ms[threadIdx.x] = amask[b*T + (c<<6) + threadIdx.x];
    __syncthreads();
    int kidx = (c<<6) + lane;
    bool valid = (kidx <= qi) && (Ms[lane] != 0);
    float dot = 0.f;
    #pragma unroll
    for (int d4=0; d4<16; ++d4){
      float4 k4 = *(const float4*)&Ks[lane][d4<<2];
      dot = fmaf(qreg[d4].x, k4.x, dot);
      dot = fmaf(qreg[d4].y, k4.y, dot);
      dot = fmaf(qreg[d4].z, k4.z, dot);
      dot = fmaf(qreg[d4].w, k4.w, dot);
    }
    float s = valid ? dot * 0.125f : -INFINITY;
    float cm = wave_max(s);
    float mnew = fmaxf(m, cm);
    float corr = (mnew > -INFINITY) ? __expf(m - mnew) : 0.f;
    float p = valid ? __expf(s - mnew) : 0.f;
    float ps = wave_sum(p);
    l = l*corr + ps;
    acc *= corr;
    Ps[wave][lane] = p;
    #pragma unroll
    for (int k4=0; k4<16; ++k4){
      float4 p4 = *(const float4*)&Ps[wave][k4<<2];
      int k0 = k4 << 2;
      acc = fmaf(p4.x, Vs[k0+0][lane], acc);
      acc = fmaf(p4.y, Vs[k0+1][lane], acc);
      acc = fmaf(p4.z, Vs[k0+2][lane], acc);
      acc = fmaf(p4.w, Vs[k0+3][lane], acc);
    }
    m = mnew;
  }
  float o = acc / l;
  f16 hh = (f16)o;
  size_t base = (size_t)(b*T + qi)*KSPL + (h<<6) + lane;
  A2out[base]     = hh;
  A2out[base + E] = (f16)(o - (float)hh);
}

// ---------------- old attention (fallback path) ----------------
__global__ __launch_bounds__(256) void attn_kernel(const float* __restrict__ Q,
    const float* __restrict__ Kg, const float* __restrict__ Vg,
    const int* __restrict__ amask, float* __restrict__ O){
  int blk = blockIdx.x;
  int qc = blk & 255;
  int bh = blk >> 8;
  int b = bh >> 3, h = bh & 7;
  int wave = threadIdx.x >> 6, lane = threadIdx.x & 63;
  int qi = (qc<<2) + wave;
  __shared__ float Ks[64][65];
  __shared__ float Vs[64][65];
  __shared__ float Qs[4][64];
  __shared__ int   Ms[64];
  const float* qp = Q + ((size_t)bh*T + qi)*HS;
  Qs[wave][lane] = qp[lane];
  const float* kb = Kg + (size_t)bh*T*HS;
  const float* vb = Vg + (size_t)bh*T*HS;
  float acc=0.f, m=-INFINITY, l=0.f;
  int nchunk = (((qc<<2)+3)>>6) + 1;
  for (int c=0;c<nchunk;++c){
    __syncthreads();
    #pragma unroll
    for (int i=0;i<4;++i){
      int fi = threadIdx.x + i*256;
      int r = fi >> 4, cc = (fi & 15) << 2;
      float4 kv = *(const float4*)(kb + (size_t)c*4096 + ((size_t)fi<<2));
      Ks[r][cc]=kv.x; Ks[r][cc+1]=kv.y; Ks[r][cc+2]=kv.z; Ks[r][cc+3]=kv.w;
      float4 vv = *(const float4*)(vb + (size_t)c*4096 + ((size_t)fi<<2));
      Vs[r][cc]=vv.x; Vs[r][cc+1]=vv.y; Vs[r][cc+2]=vv.z; Vs[r][cc+3]=vv.w;
    }
    if (threadIdx.x < 64) Ms[threadIdx.x] = amask[b*T + (c<<6) + threadIdx.x];
    __syncthreads();
    int kidx = (c<<6) + lane;
    bool valid = (kidx <= qi) && (Ms[lane] != 0);
    float dot = 0.f;
    #pragma unroll
    for (int d=0; d<64; ++d) dot = fmaf(Qs[wave][d], Ks[lane][d], dot);
    float s = valid ? dot * 0.125f : -INFINITY;
    float cm = wave_max(s);
    float mnew = fmaxf(m, cm);
    float corr = (mnew > -INFINITY) ? __expf(m - mnew) : 0.f;
    float p = valid ? __expf(s - mnew) : 0.f;
    float ps = wave_sum(p);
    l = l*corr + ps;
    acc *= corr;
    #pragma unroll
    for (int k2=0;k2<64;++k2){
      float pk = __shfl(p, k2);
      acc = fmaf(pk, Vs[k2][lane], acc);
    }
    m = mnew;
  }
  O[((size_t)b*T + qi)*E + (h<<6) + lane] = acc / l;
}

// ---------------- loss: single-pass online logsumexp per row ----------------
__global__ __launch_bounds__(256) void loss_row(const float* __restrict__ logits,
    const int* __restrict__ tgt, float* __restrict__ part){
  int row = blockIdx.x; int tid = threadIdx.x;
  const float* lr = logits + (size_t)row*V;
  float m = -INFINITY, s = 0.f;
  for (int i=tid; i<V; i+=256){
    float x = lr[i];
    if (x > m){ s = s*__expf(m - x) + 1.f; m = x; }
    else s += __expf(x - m);
  }
  for (int o=32;o;o>>=1){
    float m2 = __shfl_xor(m,o), s2 = __shfl_xor(s,o);
    lse_merge(m, s, m2, s2);
  }
  int wave=tid>>6, lane=tid&63;
  __shared__ float sm[4], ss[4];
  if (!lane){ sm[wave]=m; ss[wave]=s; }
  __syncthreads();
  if (tid==0){
    float M = sm[0], S = ss[0];
    lse_merge(M, S, sm[1], ss[1]);
    lse_merge(M, S, sm[2], ss[2]);
    lse_merge(M, S, sm[3], ss[3]);
    part[row] = M + __logf(S) - lr[tgt[row]];
  }
}

__global__ __launch_bounds__(256) void loss_final(const float* __restrict__ part, float* __restrict__ out){
  int tid = threadIdx.x;
  float s=0.f;
  for (int i=tid;i<NTOK;i+=256) s += part[i];
  s = wave_sum(s);
  __shared__ float sr[4];
  int wave=tid>>6, lane=tid&63;
  if (!lane) sr[wave]=s;
  __syncthreads();
  if (tid==0) out[0] = (sr[0]+sr[1]+sr[2]+sr[3]) * (1.f/NTOK);
}

// ---------------- embed only (fallback) ----------------
__global__ __launch_bounds__(256) void embed_kernel(const int* __restrict__ idx,
    const float* __restrict__ tok, const float* __restrict__ pos, float* __restrict__ X){
  int i = blockIdx.x*256 + threadIdx.x;
  int e = i & (E-1);
  int bt = i >> 9;
  int t = bt & (T-1);
  X[i] = tok[(size_t)idx[bt]*E + e] + pos[t*E + e];
}

extern "C" void kernel_launch(void* const* d_in, const int* in_sizes, int n_in,
                              void* d_out, int out_size, void* d_ws, size_t ws_size,
                              hipStream_t stream) {
  const int*   idx    = (const int*)  d_in[0];
  const int*   tgt    = (const int*)  d_in[1];
  const int*   amask  = (const int*)  d_in[2];
  const float* tok    = (const float*)d_in[3];
  const float* pos    = (const float*)d_in[4];
  const float* wq     = (const float*)d_in[5];
  const float* wk     = (const float*)d_in[6];
  const float* wv     = (const float*)d_in[7];
  const float* bq     = (const float*)d_in[8];
  const float* bk     = (const float*)d_in[9];
  const float* bv     = (const float*)d_in[10];
  const float* wo     = (const float*)d_in[11];
  const float* bo     = (const float*)d_in[12];
  const float* ln1g   = (const float*)d_in[13];
  const float* ln1b   = (const float*)d_in[14];
  const float* ln2g   = (const float*)d_in[15];
  const float* ln2b   = (const float*)d_in[16];
  const float* w1     = (const float*)d_in[17];
  const float* b1     = (const float*)d_in[18];
  const float* w2     = (const float*)d_in[19];
  const float* b2     = (const float*)d_in[20];
  const float* lnfg   = (const float*)d_in[21];
  const float* lnfb   = (const float*)d_in[22];
  const float* wf     = (const float*)d_in[23];
  const float* bf     = (const float*)d_in[24];

  char* wsb = (char*)d_ws;
  float* out = (float*)d_out;

  const size_t SZ = (size_t)NTOK*E;                     // floats
  const size_t OLD_BYTES = (6*SZ + (size_t)NTOK*FF + NTOK)*sizeof(float);
  bool use_mfma = (ws_size >= OLD_BYTES);

  float* X = (float*)wsb;                                        // 8.39 MB

  if (use_mfma){
    // layer-phase layout (peak 111.15 MB; ws >= 111.41 MB proven by R1-R8 gates)
    f16*   B2qkv  = (f16*)  (wsb + 8388608);     // [L][1536][512] fp16, 6.29 MB (gap region)
    float* bqkv   = (float*)(wsb + 14680064);    // [L][1536] fp32, 24.6 KB
    float* QKV    = (float*)(wsb + 16777216);    // [NTOK][1536] fp32 (25.17 MB)
    float* P4     = (float*)(wsb + 16777216);    // 4x[NTOK][512] fp32 partials (QKV+gap, dead then)
    f16*   A2a    = (f16*)  (wsb + 50331648);    // [NTOK][1024] split acts fp16, 8.39 MB
    f16*   U2     = (f16*)  (wsb + 58720256);    // [NTOK][4096] split FFN acts fp16, 33.55 MB
    f16*   B2wo   = (f16*)  (wsb + 92274688);    // [L][512][512] fp16, 2.10 MB
    f16*   B2w1   = (f16*)  (wsb + 94371840);    // [L][2048][512] fp16, 8.39 MB
    f16*   B2w2   = (f16*)  (wsb + 102760448);   // [L][512][2048] fp16, 8.39 MB (ends 111.15 MB)
    // classifier-phase layout
    const size_t B2SP_BYTES = (size_t)NPAD*512*2;          // 51,511,296
    f16*   B2sp   = (f16*)wsb;                             // [NPAD][512] fp16
    f16*   A2sp   = (f16*)(wsb + B2SP_BYTES);              // [NTOK][1024] fp16
    float* PART2  = (float*)(wsb + B2SP_BYTES + (size_t)NTOK*KSPL*2);

    // ---- all weight splits upfront, batched over layers ----
    split_wqkv_f16<<<dim3(24,8,L), 256, 0, stream>>>(wq, wk, wv, B2qkv, bq, bk, bv, bqkv);
    split_w_f16<<<dim3(8,8,L),  256, 0, stream>>>(wo, B2wo, 512, 512);
    split_w_f16<<<dim3(32,8,L), 256, 0, stream>>>(w1, B2w1, 2048, 512);
    split_w_f16<<<dim3(8,32,L), 256, 0, stream>>>(w2, B2w2, 512, 2048);

    embed_ln_split_kernel<<<NTOK, 256, 0, stream>>>(idx, tok, pos, ln1g, ln1b, X, A2a);

    for (int l=0; l<L; ++l){
      mfma_gemm_f16<false,false,false,512,1536><<<dim3(32,12,1), 256, 0, stream>>>(
          A2a, B2qkv + (size_t)l*1536*512, bqkv + (size_t)l*1536, QKV, nullptr);
      attn_fused_kernel<<<B*H*(T/4), 256, 0, stream>>>(QKV, amask, A2a);
      mfma_gemm_f16<false,false,true,512,512><<<dim3(32,4,4), 256, 0, stream>>>(
          A2a, B2wo + (size_t)l*512*512, nullptr, P4, nullptr);
      red4_ln_split_kernel<<<NTOK, 256, 0, stream>>>(
          P4, bo + (size_t)l*E, ln2g + (size_t)l*E, ln2b + (size_t)l*E, X, A2a);
      mfma_gemm_f16<true,true,false,512,2048><<<dim3(32,16,1), 256, 0, stream>>>(
          A2a, B2w1 + (size_t)l*2048*512, b1 + (size_t)l*FF, nullptr, U2);
      mfma_gemm_f16<false,false,true,2048,512><<<dim3(32,4,4), 256, 0, stream>>>(
          U2, B2w2 + (size_t)l*512*2048, nullptr, P4, nullptr);
      if (l < L-1){
        red4_ln_split_kernel<<<NTOK, 256, 0, stream>>>(
            P4, b2 + (size_t)l*E, ln1g + (size_t)(l+1)*E, ln1b + (size_t)(l+1)*E, X, A2a);
      } else {
        red4_ln_split_kernel<<<NTOK, 256, 0, stream>>>(
            P4, b2 + (size_t)l*E, lnfg, lnfb, X, A2sp);
      }
    }

    split_bT_f16<<<dim3(NPAD/64, E/64, 1), 256, 0, stream>>>(wf, B2sp);
    mfma_gemm_f16<false,false,false,512,V><<<dim3(NTOK/128, NPAD/128, 1), 256, 0, stream>>>(
        A2sp, B2sp, bf, out, nullptr);
    loss_row<<<NTOK, 256, 0, stream>>>(out, tgt, PART2);
    loss_final<<<1, 256, 0, stream>>>(PART2, out + (size_t)NTOK*V);
  } else {
    // -------- fp32 fallback (original pipeline) --------
    float* ws  = (float*)d_ws;
    float* Hb  = ws + 1*SZ;
    float* Qb  = ws + 2*SZ;
    float* Kb  = ws + 3*SZ;
    float* Vb  = ws + 4*SZ;
    float* ATT = ws + 5*SZ;
    float* U   = ws + 6*SZ;
    float* PART= ws + 6*SZ + (size_t)NTOK*FF;

    embed_kernel<<<NTOK*E/256, 256, 0, stream>>>(idx, tok, pos, X);
    for (int l=0; l<L; ++l){
      ln_kernel<<<NTOK, 256, 0, stream>>>(X, ln1g + (size_t)l*E, ln1b + (size_t)l*E, Hb);
      sgemm<false,false><<<dim3(1,T/64,B*H), 256, 0, stream>>>(
          Hb, wq + (size_t)l*H*E*HS, bq + (size_t)l*H*HS, nullptr, Qb,
          T, HS, E, H, (long long)T*E, (long long)E*HS, (long long)HS, (long long)T*HS);
      sgemm<false,false><<<dim3(1,T/64,B*H), 256, 0, stream>>>(
          Hb, wk + (size_t)l*H*E*HS, bk + (size_t)l*H*HS, nullptr, Kb,
          T, HS, E, H, (long long)T*E, (long long)E*HS, (long long)HS, (long long)T*HS);
      sgemm<false,false><<<dim3(1,T/64,B*H), 256, 0, stream>>>(
          Hb, wv + (size_t)l*H*E*HS, bv + (size_t)l*H*HS, nullptr, Vb,
          T, HS, E, H, (long long)T*E, (long long)E*HS, (long long)HS, (long long)T*HS);
      attn_kernel<<<B*H*(T/4), 256, 0, stream>>>(Qb, Kb, Vb, amask, ATT);
      sgemm<false,true><<<dim3(E/64, NTOK/64, 1), 256, 0, stream>>>(
          ATT, wo + (size_t)l*E*E, bo + (size_t)l*E, X, X,
          NTOK, E, E, 1, 0,0,0,0);
      ln_kernel<<<NTOK, 256, 0, stream>>>(X, ln2g + (size_t)l*E, ln2b + (size_t)l*E, Hb);
      sgemm<true,false><<<dim3(FF/64, NTOK/64, 1), 256, 0, stream>>>(
          Hb, w1 + (size_t)l*E*FF, b1 + (size_t)l*FF, nullptr, U,
          NTOK, FF, E, 1, 0,0,0,0);
      sgemm<false,true><<<dim3(E/64, NTOK/64, 1), 256, 0, stream>>>(
          U, w2 + (size_t)l*FF*E, b2 + (size_t)l*E, X, X,
          NTOK, E, FF, 1, 0,0,0,0);
    }
    ln_kernel<<<NTOK, 256, 0, stream>>>(X, lnfg, lnfb, Hb);
    sgemm<false,false><<<dim3((V+63)/64, NTOK/64, 1), 256, 0, stream>>>(
        Hb, wf, bf, nullptr, out, NTOK, V, E, 1, 0,0,0,0);
    loss_row<<<NTOK, 256, 0, stream>>>(out, tgt, PART);
    loss_final<<<1, 256, 0, stream>>>(PART, out + (size_t)NTOK*V);
  }
}

// Round 15
// 2420.960 us; speedup vs baseline: 1.0390x; 1.0390x over previous
//
#include <hip/hip_runtime.h>
#include <math.h>

#define E 512
#define V 50257
#define T 1024
#define B 4
#define H 8
#define HS 64
#define L 4
#define FF 2048
#define NTOK 4096   // B*T

#define NPAD 50304  // 393*128, padded V for MFMA tiles
#define KSPL 1024   // split row length for K=512: [hi(512) | lo(512)]

typedef _Float16 f16;
typedef _Float16 f16x8 __attribute__((ext_vector_type(8)));
typedef float    f32x4 __attribute__((ext_vector_type(4)));

__device__ inline float wave_max(float v){ for(int o=32;o;o>>=1) v=fmaxf(v,__shfl_xor(v,o)); return v; }
__device__ inline float wave_sum(float v){ for(int o=32;o;o>>=1) v+=__shfl_xor(v,o); return v; }

// online-LSE merge with -inf guard
__device__ inline void lse_merge(float& m, float& s, float m2, float s2){
  float mn = fmaxf(m, m2);
  if (mn == -INFINITY){ m = mn; s = 0.f; return; }
  s = s*__expf(m - mn) + s2*__expf(m2 - mn);
  m = mn;
}

// ---------------- embedding fused with ln1 + split-fp16 output ----------------
__global__ __launch_bounds__(256) void embed_ln_split_kernel(const int* __restrict__ idx,
    const float* __restrict__ tok, const float* __restrict__ pos,
    const float* __restrict__ g, const float* __restrict__ bb,
    float* __restrict__ X, f16* __restrict__ A2){
  int row = blockIdx.x; int tid = threadIdx.x;
  int t = row & (T-1);
  const float* te = tok + (size_t)idx[row]*E;
  const float* pe = pos + (size_t)t*E;
  float v0 = te[tid] + pe[tid];
  float v1 = te[tid+256] + pe[tid+256];
  float* xr = X + (size_t)row*E;
  xr[tid] = v0; xr[tid+256] = v1;
  int wave = tid>>6, lane = tid&63;
  __shared__ float r1[4], r2[4];
  float s = wave_sum(v0+v1);
  if (!lane) r1[wave]=s;
  __syncthreads();
  float mean = (r1[0]+r1[1]+r1[2]+r1[3]) * (1.f/E);
  float d0=v0-mean, d1=v1-mean;
  float vs = wave_sum(d0*d0+d1*d1);
  if (!lane) r2[wave]=vs;
  __syncthreads();
  float var = (r2[0]+r2[1]+r2[2]+r2[3]) * (1.f/E);
  float rs = rsqrtf(var + 1e-5f);
  float y0 = d0*rs*g[tid]     + bb[tid];
  float y1 = d1*rs*g[tid+256] + bb[tid+256];
  size_t base = (size_t)row*KSPL;
  f16 h0=(f16)y0, h1=(f16)y1;
  A2[base + tid]         = h0;
  A2[base + E + tid]     = (f16)(y0 - (float)h0);
  A2[base + tid+256]     = h1;
  A2[base + E + tid+256] = (f16)(y1 - (float)h1);
}

// ---------------- reduce 4 partials + bias into X, fused with next LN + split-fp16 ----------------
__global__ __launch_bounds__(256) void red4_ln_split_kernel(const float* __restrict__ P,
    const float* __restrict__ bias, const float* __restrict__ g, const float* __restrict__ bb,
    float* __restrict__ X, f16* __restrict__ A2){
  int row = blockIdx.x; int tid = threadIdx.x;
  const size_t STRIDE = (size_t)NTOK*E;
  size_t i0 = (size_t)row*E + tid, i1 = i0 + 256;
  float v0 = X[i0] + P[i0] + P[i0+STRIDE] + P[i0+2*STRIDE] + P[i0+3*STRIDE] + bias[tid];
  float v1 = X[i1] + P[i1] + P[i1+STRIDE] + P[i1+2*STRIDE] + P[i1+3*STRIDE] + bias[tid+256];
  X[i0] = v0; X[i1] = v1;
  int wave = tid>>6, lane = tid&63;
  __shared__ float r1[4], r2[4];
  float s = wave_sum(v0+v1);
  if (!lane) r1[wave]=s;
  __syncthreads();
  float mean = (r1[0]+r1[1]+r1[2]+r1[3]) * (1.f/E);
  float d0=v0-mean, d1=v1-mean;
  float vs = wave_sum(d0*d0+d1*d1);
  if (!lane) r2[wave]=vs;
  __syncthreads();
  float var = (r2[0]+r2[1]+r2[2]+r2[3]) * (1.f/E);
  float rs = rsqrtf(var + 1e-5f);
  float y0 = d0*rs*g[tid]     + bb[tid];
  float y1 = d1*rs*g[tid+256] + bb[tid+256];
  size_t base = (size_t)row*KSPL;
  f16 h0=(f16)y0, h1=(f16)y1;
  A2[base + tid]         = h0;
  A2[base + E + tid]     = (f16)(y0 - (float)h0);
  A2[base + tid+256]     = h1;
  A2[base + E + tid+256] = (f16)(y1 - (float)h1);
}

// ---------------- layernorm (fp32 out, fallback path) ----------------
__global__ __launch_bounds__(256) void ln_kernel(const float* __restrict__ X,
    const float* __restrict__ g, const float* __restrict__ bb, float* __restrict__ O){
  int row = blockIdx.x; int tid = threadIdx.x;
  const float* x = X + (size_t)row*E;
  float v0 = x[tid], v1 = x[tid+256];
  int wave = tid>>6, lane = tid&63;
  __shared__ float r1[4], r2[4];
  float s = wave_sum(v0+v1);
  if (!lane) r1[wave]=s;
  __syncthreads();
  float mean = (r1[0]+r1[1]+r1[2]+r1[3]) * (1.f/E);
  float d0=v0-mean, d1=v1-mean;
  float vs = wave_sum(d0*d0+d1*d1);
  if (!lane) r2[wave]=vs;
  __syncthreads();
  float var = (r2[0]+r2[1]+r2[2]+r2[3]) * (1.f/E);
  float rs = rsqrtf(var + 1e-5f);
  float* o = O + (size_t)row*E;
  o[tid]     = d0*rs*g[tid]     + bb[tid];
  o[tid+256] = d1*rs*g[tid+256] + bb[tid+256];
}

// ---------------- tiled SGEMM (fp32 vector path, fallback only) ----------------
template<bool RELU, bool RESID>
__global__ __launch_bounds__(256) void sgemm(const float* __restrict__ A, const float* __restrict__ Bm,
    const float* __restrict__ bias, const float* __restrict__ Rs, float* __restrict__ C,
    int M, int N, int K, int Hn,
    long long sA, long long sB, long long sBias, long long sC){
  int z = blockIdx.z;
  A    += (long long)(z / Hn) * sA;
  Bm   += (long long)(z % Hn) * sB;
  bias += (long long)(z % Hn) * sBias;
  C    += (long long)z * sC;
  __shared__ float As[16][68];
  __shared__ float Bs[16][64];
  int tid = threadIdx.x;
  int tx = tid & 15, ty = tid >> 4;
  int m0 = blockIdx.y * 64, n0 = blockIdx.x * 64;
  int ar = tid >> 2, ac = (tid & 3) << 2;
  int br = tid >> 4, bc = (tid & 15) << 2;
  float acc[4][4] = {};
  const float* Ap = A + (size_t)(m0+ar)*K + ac;
  const float* Bp = Bm + (size_t)br*N + n0 + bc;
  int bn = n0 + bc;
  for (int k0=0; k0<K; k0+=16){
    float4 av = *(const float4*)Ap;
    As[ac+0][ar]=av.x; As[ac+1][ar]=av.y; As[ac+2][ar]=av.z; As[ac+3][ar]=av.w;
    float4 bv;
    if (bn+3 < N) bv = *(const float4*)Bp;
    else {
      bv.x = (bn+0<N)?Bp[0]:0.f; bv.y=(bn+1<N)?Bp[1]:0.f;
      bv.z = (bn+2<N)?Bp[2]:0.f; bv.w=(bn+3<N)?Bp[3]:0.f;
    }
    *(float4*)&Bs[br][bc] = bv;
    __syncthreads();
    #pragma unroll
    for (int kk=0; kk<16; ++kk){
      float4 a4 = *(const float4*)&As[kk][ty<<2];
      float4 b4 = *(const float4*)&Bs[kk][tx<<2];
      acc[0][0] = fmaf(a4.x,b4.x,acc[0][0]); acc[0][1] = fmaf(a4.x,b4.y,acc[0][1]);
      acc[0][2] = fmaf(a4.x,b4.z,acc[0][2]); acc[0][3] = fmaf(a4.x,b4.w,acc[0][3]);
      acc[1][0] = fmaf(a4.y,b4.x,acc[1][0]); acc[1][1] = fmaf(a4.y,b4.y,acc[1][1]);
      acc[1][2] = fmaf(a4.y,b4.z,acc[1][2]); acc[1][3] = fmaf(a4.y,b4.w,acc[1][3]);
      acc[2][0] = fmaf(a4.z,b4.x,acc[2][0]); acc[2][1] = fmaf(a4.z,b4.y,acc[2][1]);
      acc[2][2] = fmaf(a4.z,b4.z,acc[2][2]); acc[2][3] = fmaf(a4.z,b4.w,acc[2][3]);
      acc[3][0] = fmaf(a4.w,b4.x,acc[3][0]); acc[3][1] = fmaf(a4.w,b4.y,acc[3][1]);
      acc[3][2] = fmaf(a4.w,b4.z,acc[3][2]); acc[3][3] = fmaf(a4.w,b4.w,acc[3][3]);
    }
    __syncthreads();
    Ap += 16; Bp += (size_t)16*N;
  }
  #pragma unroll
  for (int i=0;i<4;++i){
    int row = m0 + (ty<<2) + i;
    float* crow = C + (size_t)row*N;
    #pragma unroll
    for (int j=0;j<4;++j){
      int col = n0 + (tx<<2) + j;
      if (col < N){
        float vv = acc[i][j] + bias[col];
        if (RESID) vv += Rs[(size_t)row*N + col];
        if (RELU)  vv = fmaxf(vv, 0.f);
        crow[col] = vv;
      }
    }
  }
}

// ================= fp16 A-split MFMA GEMM machinery =================
// C = Ahi*B + Alo*B  (A repr error ~2^-22; B fp16 rounding ~2^-11 rel)

#define GLOBAL_AS __attribute__((address_space(1)))
#define LDS_AS    __attribute__((address_space(3)))

__device__ inline void gll16(const void* g, void* l){
  __builtin_amdgcn_global_load_lds((const GLOBAL_AS void*)g, (LDS_AS void*)l, 16, 0, 0);
}

// transpose+convert, ALL LAYERS batched on z: W[z] [K][N] fp32 -> B1[z] [N][K] fp16
__global__ __launch_bounds__(256) void split_w_f16(const float* __restrict__ W,
    f16* __restrict__ B1, int N, int K){
  __shared__ float S[64][65];
  int n0 = blockIdx.x * 64;
  int k0 = blockIdx.y * 64;
  int lz = blockIdx.z;
  W  += (size_t)lz * ((size_t)K * N);
  B1 += (size_t)lz * ((size_t)N * K);
  int t = threadIdx.x;
  #pragma unroll
  for (int p=0;p<16;++p){
    int e = p*256 + t;
    int kl = e >> 6, nl = e & 63;
    S[kl][nl] = W[(size_t)(k0+kl)*N + n0+nl];
  }
  __syncthreads();
  #pragma unroll
  for (int p=0;p<16;++p){
    int e = p*256 + t;
    int nl = e >> 6, kl = e & 63;
    B1[(size_t)(n0+nl)*(size_t)K + (k0+kl)] = (f16)S[kl][nl];
  }
}

// fused qkv weights + bias concat, ALL LAYERS on z: -> B1[z] [1536][512], bqkv[z][1536]
__global__ __launch_bounds__(256) void split_wqkv_f16(const float* __restrict__ wq,
    const float* __restrict__ wk, const float* __restrict__ wv, f16* __restrict__ B1,
    const float* __restrict__ bq, const float* __restrict__ bk, const float* __restrict__ bv,
    float* __restrict__ bqkv){
  int lz = blockIdx.z;
  wq += (size_t)lz*H*E*HS; wk += (size_t)lz*H*E*HS; wv += (size_t)lz*H*E*HS;
  bq += (size_t)lz*H*HS;   bk += (size_t)lz*H*HS;   bv += (size_t)lz*H*HS;
  B1 += (size_t)lz*1536*512; bqkv += (size_t)lz*1536;
  if (blockIdx.x == 0 && blockIdx.y == 0){
    for (int i=threadIdx.x; i<1536; i+=256)
      bqkv[i] = (i < 512) ? bq[i] : (i < 1024 ? bk[i-512] : bv[i-1024]);
  }
  __shared__ float S[64][65];
  int n0 = blockIdx.x * 64;   // 24 tiles
  int e0 = blockIdx.y * 64;   // 8 tiles
  const float* W; int nloc;
  if (n0 < 512){ W = wq; nloc = n0; }
  else if (n0 < 1024){ W = wk; nloc = n0 - 512; }
  else { W = wv; nloc = n0 - 1024; }
  int h = nloc >> 6;
  int t = threadIdx.x;
  #pragma unroll
  for (int p=0;p<16;++p){
    int idx2 = p*256 + t;
    int e = idx2 >> 6, o = idx2 & 63;
    S[e][o] = W[((size_t)(h*E + e0 + e))*HS + o];
  }
  __syncthreads();
  #pragma unroll
  for (int p=0;p<16;++p){
    int idx2 = p*256 + t;
    int r = idx2 >> 6, c = idx2 & 63;
    B1[(size_t)(n0 + r)*512 + (e0 + c)] = (f16)S[c][r];
  }
}

// transpose+convert wf [E][V] -> B1 [NPAD][512] fp16, zero rows n>=V
__global__ __launch_bounds__(256) void split_bT_f16(const float* __restrict__ Wf, f16* __restrict__ B1){
  __shared__ float S[64][65];
  int n0 = blockIdx.x * 64;
  int k0 = blockIdx.y * 64;
  int t = threadIdx.x;
  #pragma unroll
  for (int p=0;p<16;++p){
    int e = p*256 + t;
    int kl = e >> 6, nl = e & 63;
    int n = n0 + nl;
    S[kl][nl] = (n < V) ? Wf[(size_t)(k0+kl)*V + n] : 0.f;
  }
  __syncthreads();
  #pragma unroll
  for (int p=0;p<16;++p){
    int e = p*256 + t;
    int nl = e >> 6, kl = e & 63;
    B1[(size_t)(n0+nl)*512 + (k0+kl)] = (f16)S[kl][nl];
  }
}

// fp16 MFMA GEMM: C[NTOK,NLOG] = A2[NTOK][2K](hi|lo fp16) x B1[Npad][K]^T (fp16)
// 128x128 tile, BK=64, 4 waves, 16x16x32 f16, XOR-swizzled LDS (2-way = free),
// global_load_lds staging. 2 passes (hi, lo) in-block. R13-proven: VGPR 80, 0 conflicts.
// PARTIAL4: blockIdx.z = (term<<1)|khalf; raw partial -> C + z*NTOK*NLOG (bias in reduce).
template<bool RELU, bool OUTSPLIT, bool PARTIAL4, int K, int NLOG>
__global__ __launch_bounds__(256) void mfma_gemm_f16(
    const f16* __restrict__ A2, const f16* __restrict__ B1,
    const float* __restrict__ bias, float* __restrict__ C, f16* __restrict__ C2){
  __shared__ f16 As[128*64];
  __shared__ f16 Bs[128*64];
  int tid = threadIdx.x;
  int lane = tid & 63, wv = tid >> 6;
  int wm = wv >> 1, wn = wv & 1;
  int m0 = blockIdx.x * 128;
  int n0 = blockIdx.y * 128;

  f32x4 acc[4][4];
  #pragma unroll
  for (int i=0;i<4;++i)
    #pragma unroll
    for (int j=0;j<4;++j){ f32x4 z = {0.f,0.f,0.f,0.f}; acc[i][j] = z; }

  constexpr size_t LDA = (size_t)(4*K);   // A row = 2K fp16
  constexpr size_t LDB = (size_t)(2*K);   // B row = K fp16
  const char* Abase = (const char*)A2 + (size_t)m0*LDA;
  const char* Bbase = (const char*)B1 + (size_t)n0*LDB;
  int halfm = wm*64, halfn = wn*64;

  constexpr int NPS = PARTIAL4 ? 1 : 2;
  constexpr int KRANGE = PARTIAL4 ? (K/2) : K;
  int kbase = PARTIAL4 ? ((int)blockIdx.z & 1)*(K/2) : 0;
  #pragma unroll
  for (int pi=0; pi<NPS; ++pi){
    int term = PARTIAL4 ? ((int)blockIdx.z >> 1) : pi;
    size_t abyte = ((size_t)term*K + (size_t)kbase)*2;
    size_t bbyte = (size_t)kbase*2;
    for (int kk=0; kk<KRANGE; kk+=64){
      const char* Ak = Abase + abyte + (size_t)kk*2;
      const char* Bk = Bbase + bbyte + (size_t)kk*2;
      #pragma unroll
      for (int p=0;p<4;++p){
        int slot = p*256 + tid;
        int row  = slot >> 3;
        int sch  = (slot & 7) ^ (row & 7);
        gll16(Ak + (size_t)row*LDA + (sch<<4), (char*)As + (p<<12) + (wv<<10));
      }
      #pragma unroll
      for (int p=0;p<4;++p){
        int slot = p*256 + tid;
        int row  = slot >> 3;
        int sch  = (slot & 7) ^ (row & 7);
        gll16(Bk + (size_t)row*LDB + (sch<<4), (char*)Bs + (p<<12) + (wv<<10));
      }
      __syncthreads();
      #pragma unroll
      for (int kp=0; kp<2; ++kp){
        f16x8 af[4], bfr[4];
        int chq = kp*4 + (lane >> 4);
        #pragma unroll
        for (int mf=0; mf<4; ++mf){
          int r = halfm + mf*16 + (lane & 15);
          int sch = chq ^ (r & 7);
          af[mf] = *(const f16x8*)((const char*)As + r*128 + (sch<<4));
        }
        #pragma unroll
        for (int nf=0; nf<4; ++nf){
          int r = halfn + nf*16 + (lane & 15);
          int sch = chq ^ (r & 7);
          bfr[nf] = *(const f16x8*)((const char*)Bs + r*128 + (sch<<4));
        }
        #pragma unroll
        for (int mf=0; mf<4; ++mf)
          #pragma unroll
          for (int nf=0; nf<4; ++nf)
            acc[mf][nf] = __builtin_amdgcn_mfma_f32_16x16x32_f16(af[mf], bfr[nf], acc[mf][nf], 0, 0, 0);
      }
      __syncthreads();
    }
  }
  float* Cp = C;
  if (PARTIAL4) Cp += (size_t)blockIdx.z * ((size_t)NTOK*NLOG);
  #pragma unroll
  for (int mf=0; mf<4; ++mf){
    int row = m0 + halfm + mf*16 + ((lane>>4)<<2);
    #pragma unroll
    for (int nf=0; nf<4; ++nf){
      int col = n0 + halfn + nf*16 + (lane & 15);
      if (col < NLOG){
        #pragma unroll
        for (int r=0;r<4;++r){
          float vv = acc[mf][nf][r];
          if (PARTIAL4){
            Cp[(size_t)(row+r)*NLOG + col] = vv;        // raw partial, bias in reduce
          } else if (OUTSPLIT){
            vv += bias[col];
            if (RELU) vv = fmaxf(vv, 0.f);
            f16 h = (f16)vv;
            C2[(size_t)(row+r)*(2*(size_t)NLOG) + col]        = h;
            C2[(size_t)(row+r)*(2*(size_t)NLOG) + NLOG + col] = (f16)(vv - (float)h);
          } else {
            vv += bias[col];
            if (RELU) vv = fmaxf(vv, 0.f);
            Cp[(size_t)(row+r)*NLOG + col] = vv;
          }
        }
      }
    }
  }
}

// ---------------- flash attention on fused QKV [B,T,1536]; writes split-fp16 output ----------------
// R11-proven: Q in registers (wave-uniform), aligned 68-float LDS rows, PV p via LDS b128 broadcast.
__global__ __launch_bounds__(256) void attn_fused_kernel(const float* __restrict__ QKV,
    const int* __restrict__ amask, f16* __restrict__ A2out){
  int blk = blockIdx.x;
  int qc = blk & 255;
  int bh = blk >> 8;
  int b = bh >> 3, h = bh & 7;
  int wave = threadIdx.x >> 6, lane = threadIdx.x & 63;
  int qi = (qc<<2) + wave;
  __shared__ float Ks[64][68];
  __shared__ float Vs[64][68];
  __shared__ float Ps[4][64];
  __shared__ int   Ms[64];
  const float* qrow = QKV + (size_t)(b*T + qi)*1536 + (h<<6);
  float4 qreg[16];
  #pragma unroll
  for (int d4=0; d4<16; ++d4) qreg[d4] = *(const float4*)(qrow + (d4<<2));
  const float* kb = QKV + (size_t)(b*T)*1536 + 512 + (h<<6);
  float acc=0.f, m=-INFINITY, l=0.f;
  int nchunk = (((qc<<2)+3)>>6) + 1;
  for (int c=0;c<nchunk;++c){
    __syncthreads();
    #pragma unroll
    for (int i=0;i<4;++i){
      int fi = threadIdx.x + i*256;
      int r = fi >> 4, f4 = fi & 15;
      const float* krow = kb + (size_t)(c*64 + r)*1536 + (f4<<2);
      float4 kv = *(const float4*)krow;
      float4 vv = *(const float4*)(krow + 512);
      int cc = f4 << 2;
      *(float4*)&Ks[r][cc] = kv;
      *(float4*)&Vs[r][cc] = vv;
    }
    if (threadIdx.x < 64) Ms[threadIdx.x] = amask[b*T + (c<<6) + threadIdx.x];
    __syncthreads();
    int kidx = (c<<6) + lane;
    bool valid = (kidx <= qi) && (Ms[lane] != 0);
    float dot = 0.f;
    #pragma unroll
    for (int d4=0; d4<16; ++d4){
      float4 k4 = *(const float4*)&Ks[lane][d4<<2];
      dot = fmaf(qreg[d4].x, k4.x, dot);
      dot = fmaf(qreg[d4].y, k4.y, dot);
      dot = fmaf(qreg[d4].z, k4.z, dot);
      dot = fmaf(qreg[d4].w, k4.w, dot);
    }
    float s = valid ? dot * 0.125f : -INFINITY;
    float cm = wave_max(s);
    float mnew = fmaxf(m, cm);
    float corr = (mnew > -INFINITY) ? __expf(m - mnew) : 0.f;
    float p = valid ? __expf(s - mnew) : 0.f;
    float ps = wave_sum(p);
    l = l*corr + ps;
    acc *= corr;
    Ps[wave][lane] = p;
    #pragma unroll
    for (int k4=0; k4<16; ++k4){
      float4 p4 = *(const float4*)&Ps[wave][k4<<2];
      int k0 = k4 << 2;
      acc = fmaf(p4.x, Vs[k0+0][lane], acc);
      acc = fmaf(p4.y, Vs[k0+1][lane], acc);
      acc = fmaf(p4.z, Vs[k0+2][lane], acc);
      acc = fmaf(p4.w, Vs[k0+3][lane], acc);
    }
    m = mnew;
  }
  float o = acc / l;
  f16 hh = (f16)o;
  size_t base = (size_t)(b*T + qi)*KSPL + (h<<6) + lane;
  A2out[base]     = hh;
  A2out[base + E] = (f16)(o - (float)hh);
}

// ---------------- old attention (fallback path) ----------------
__global__ __launch_bounds__(256) void attn_kernel(const float* __restrict__ Q,
    const float* __restrict__ Kg, const float* __restrict__ Vg,
    const int* __restrict__ amask, float* __restrict__ O){
  int blk = blockIdx.x;
  int qc = blk & 255;
  int bh = blk >> 8;
  int b = bh >> 3, h = bh & 7;
  int wave = threadIdx.x >> 6, lane = threadIdx.x & 63;
  int qi = (qc<<2) + wave;
  __shared__ float Ks[64][65];
  __shared__ float Vs[64][65];
  __shared__ float Qs[4][64];
  __shared__ int   Ms[64];
  const float* qp = Q + ((size_t)bh*T + qi)*HS;
  Qs[wave][lane] = qp[lane];
  const float* kb = Kg + (size_t)bh*T*HS;
  const float* vb = Vg + (size_t)bh*T*HS;
  float acc=0.f, m=-INFINITY, l=0.f;
  int nchunk = (((qc<<2)+3)>>6) + 1;
  for (int c=0;c<nchunk;++c){
    __syncthreads();
    #pragma unroll
    for (int i=0;i<4;++i){
      int fi = threadIdx.x + i*256;
      int r = fi >> 4, cc = (fi & 15) << 2;
      float4 kv = *(const float4*)(kb + (size_t)c*4096 + ((size_t)fi<<2));
      Ks[r][cc]=kv.x; Ks[r][cc+1]=kv.y; Ks[r][cc+2]=kv.z; Ks[r][cc+3]=kv.w;
      float4 vv = *(const float4*)(vb + (size_t)c*4096 + ((size_t)fi<<2));
      Vs[r][cc]=vv.x; Vs[r][cc+1]=vv.y; Vs[r][cc+2]=vv.z; Vs[r][cc+3]=vv.w;
    }
    if (threadIdx.x < 64) Ms[threadIdx.x] = amask[b*T + (c<<6) + threadIdx.x];
    __syncthreads();
    int kidx = (c<<6) + lane;
    bool valid = (kidx <= qi) && (Ms[lane] != 0);
    float dot = 0.f;
    #pragma unroll
    for (int d=0; d<64; ++d) dot = fmaf(Qs[wave][d], Ks[lane][d], dot);
    float s = valid ? dot * 0.125f : -INFINITY;
    float cm = wave_max(s);
    float mnew = fmaxf(m, cm);
    float corr = (mnew > -INFINITY) ? __expf(m - mnew) : 0.f;
    float p = valid ? __expf(s - mnew) : 0.f;
    float ps = wave_sum(p);
    l = l*corr + ps;
    acc *= corr;
    #pragma unroll
    for (int k2=0;k2<64;++k2){
      float pk = __shfl(p, k2);
      acc = fmaf(pk, Vs[k2][lane], acc);
    }
    m = mnew;
  }
  O[((size_t)b*T + qi)*E + (h<<6) + lane] = acc / l;
}

// ---------------- loss: single-pass online logsumexp per row ----------------
__global__ __launch_bounds__(256) void loss_row(const float* __restrict__ logits,
    const int* __restrict__ tgt, float* __restrict__ part){
  int row = blockIdx.x; int tid = threadIdx.x;
  const float* lr = logits + (size_t)row*V;
  float m = -INFINITY, s = 0.f;
  for (int i=tid; i<V; i+=256){
    float x = lr[i];
    if (x > m){ s = s*__expf(m - x) + 1.f; m = x; }
    else s += __expf(x - m);
  }
  for (int o=32;o;o>>=1){
    float m2 = __shfl_xor(m,o), s2 = __shfl_xor(s,o);
    lse_merge(m, s, m2, s2);
  }
  int wave=tid>>6, lane=tid&63;
  __shared__ float sm[4], ss[4];
  if (!lane){ sm[wave]=m; ss[wave]=s; }
  __syncthreads();
  if (tid==0){
    float M = sm[0], S = ss[0];
    lse_merge(M, S, sm[1], ss[1]);
    lse_merge(M, S, sm[2], ss[2]);
    lse_merge(M, S, sm[3], ss[3]);
    part[row] = M + __logf(S) - lr[tgt[row]];
  }
}

__global__ __launch_bounds__(256) void loss_final(const float* __restrict__ part, float* __restrict__ out){
  int tid = threadIdx.x;
  float s=0.f;
  for (int i=tid;i<NTOK;i+=256) s += part[i];
  s = wave_sum(s);
  __shared__ float sr[4];
  int wave=tid>>6, lane=tid&63;
  if (!lane) sr[wave]=s;
  __syncthreads();
  if (tid==0) out[0] = (sr[0]+sr[1]+sr[2]+sr[3]) * (1.f/NTOK);
}

// ---------------- embed only (fallback) ----------------
__global__ __launch_bounds__(256) void embed_kernel(const int* __restrict__ idx,
    const float* __restrict__ tok, const float* __restrict__ pos, float* __restrict__ X){
  int i = blockIdx.x*256 + threadIdx.x;
  int e = i & (E-1);
  int bt = i >> 9;
  int t = bt & (T-1);
  X[i] = tok[(size_t)idx[bt]*E + e] + pos[t*E + e];
}

extern "C" void kernel_launch(void* const* d_in, const int* in_sizes, int n_in,
                              void* d_out, int out_size, void* d_ws, size_t ws_size,
                              hipStream_t stream) {
  const int*   idx    = (const int*)  d_in[0];
  const int*   tgt    = (const int*)  d_in[1];
  const int*   amask  = (const int*)  d_in[2];
  const float* tok    = (const float*)d_in[3];
  const float* pos    = (const float*)d_in[4];
  const float* wq     = (const float*)d_in[5];
  const float* wk     = (const float*)d_in[6];
  const float* wv     = (const float*)d_in[7];
  const float* bq     = (const float*)d_in[8];
  const float* bk     = (const float*)d_in[9];
  const float* bv     = (const float*)d_in[10];
  const float* wo     = (const float*)d_in[11];
  const float* bo     = (const float*)d_in[12];
  const float* ln1g   = (const float*)d_in[13];
  const float* ln1b   = (const float*)d_in[14];
  const float* ln2g   = (const float*)d_in[15];
  const float* ln2b   = (const float*)d_in[16];
  const float* w1     = (const float*)d_in[17];
  const float* b1     = (const float*)d_in[18];
  const float* w2     = (const float*)d_in[19];
  const float* b2     = (const float*)d_in[20];
  const float* lnfg   = (const float*)d_in[21];
  const float* lnfb   = (const float*)d_in[22];
  const float* wf     = (const float*)d_in[23];
  const float* bf     = (const float*)d_in[24];

  char* wsb = (char*)d_ws;
  float* out = (float*)d_out;

  const size_t SZ = (size_t)NTOK*E;                     // floats
  const size_t OLD_BYTES = (6*SZ + (size_t)NTOK*FF + NTOK)*sizeof(float);
  bool use_mfma = (ws_size >= OLD_BYTES);

  float* X = (float*)wsb;                                        // 8.39 MB

  if (use_mfma){
    // layer-phase layout (peak 111.15 MB; ws >= 111.41 MB proven by R1-R8 gates)
    f16*   B2qkv  = (f16*)  (wsb + 8388608);     // [L][1536][512] fp16, 6.29 MB (gap region)
    float* bqkv   = (float*)(wsb + 14680064);    // [L][1536] fp32, 24.6 KB
    float* QKV    = (float*)(wsb + 16777216);    // [NTOK][1536] fp32 (25.17 MB)
    float* P4     = (float*)(wsb + 16777216);    // 4x[NTOK][512] fp32 partials (QKV+gap, dead then)
    f16*   A2a    = (f16*)  (wsb + 50331648);    // [NTOK][1024] split acts fp16, 8.39 MB
    f16*   U2     = (f16*)  (wsb + 58720256);    // [NTOK][4096] split FFN acts fp16, 33.55 MB
    f16*   B2wo   = (f16*)  (wsb + 92274688);    // [L][512][512] fp16, 2.10 MB
    f16*   B2w1   = (f16*)  (wsb + 94371840);    // [L][2048][512] fp16, 8.39 MB
    f16*   B2w2   = (f16*)  (wsb + 102760448);   // [L][512][2048] fp16, 8.39 MB (ends 111.15 MB)
    // classifier-phase layout
    const size_t B2SP_BYTES = (size_t)NPAD*512*2;          // 51,511,296
    f16*   B2sp   = (f16*)wsb;                             // [NPAD][512] fp16
    f16*   A2sp   = (f16*)(wsb + B2SP_BYTES);              // [NTOK][1024] fp16
    float* PART2  = (float*)(wsb + B2SP_BYTES + (size_t)NTOK*KSPL*2);

    // ---- all weight splits upfront, batched over layers ----
    split_wqkv_f16<<<dim3(24,8,L), 256, 0, stream>>>(wq, wk, wv, B2qkv, bq, bk, bv, bqkv);
    split_w_f16<<<dim3(8,8,L),  256, 0, stream>>>(wo, B2wo, 512, 512);
    split_w_f16<<<dim3(32,8,L), 256, 0, stream>>>(w1, B2w1, 2048, 512);
    split_w_f16<<<dim3(8,32,L), 256, 0, stream>>>(w2, B2w2, 512, 2048);

    embed_ln_split_kernel<<<NTOK, 256, 0, stream>>>(idx, tok, pos, ln1g, ln1b, X, A2a);

    for (int l=0; l<L; ++l){
      mfma_gemm_f16<false,false,false,512,1536><<<dim3(32,12,1), 256, 0, stream>>>(
          A2a, B2qkv + (size_t)l*1536*512, bqkv + (size_t)l*1536, QKV, nullptr);
      attn_fused_kernel<<<B*H*(T/4), 256, 0, stream>>>(QKV, amask, A2a);
      mfma_gemm_f16<false,false,true,512,512><<<dim3(32,4,4), 256, 0, stream>>>(
          A2a, B2wo + (size_t)l*512*512, nullptr, P4, nullptr);
      red4_ln_split_kernel<<<NTOK, 256, 0, stream>>>(
          P4, bo + (size_t)l*E, ln2g + (size_t)l*E, ln2b + (size_t)l*E, X, A2a);
      mfma_gemm_f16<true,true,false,512,2048><<<dim3(32,16,1), 256, 0, stream>>>(
          A2a, B2w1 + (size_t)l*2048*512, b1 + (size_t)l*FF, nullptr, U2);
      mfma_gemm_f16<false,false,true,2048,512><<<dim3(32,4,4), 256, 0, stream>>>(
          U2, B2w2 + (size_t)l*512*2048, nullptr, P4, nullptr);
      if (l < L-1){
        red4_ln_split_kernel<<<NTOK, 256, 0, stream>>>(
            P4, b2 + (size_t)l*E, ln1g + (size_t)(l+1)*E, ln1b + (size_t)(l+1)*E, X, A2a);
      } else {
        red4_ln_split_kernel<<<NTOK, 256, 0, stream>>>(
            P4, b2 + (size_t)l*E, lnfg, lnfb, X, A2sp);
      }
    }

    split_bT_f16<<<dim3(NPAD/64, E/64, 1), 256, 0, stream>>>(wf, B2sp);
    mfma_gemm_f16<false,false,false,512,V><<<dim3(NTOK/128, NPAD/128, 1), 256, 0, stream>>>(
        A2sp, B2sp, bf, out, nullptr);
    loss_row<<<NTOK, 256, 0, stream>>>(out, tgt, PART2);
    loss_final<<<1, 256, 0, stream>>>(PART2, out + (size_t)NTOK*V);
  } else {
    // -------- fp32 fallback (original pipeline) --------
    float* ws  = (float*)d_ws;
    float* Hb  = ws + 1*SZ;
    float* Qb  = ws + 2*SZ;
    float* Kb  = ws + 3*SZ;
    float* Vb  = ws + 4*SZ;
    float* ATT = ws + 5*SZ;
    float* U   = ws + 6*SZ;
    float* PART= ws + 6*SZ + (size_t)NTOK*FF;

    embed_kernel<<<NTOK*E/256, 256, 0, stream>>>(idx, tok, pos, X);
    for (int l=0; l<L; ++l){
      ln_kernel<<<NTOK, 256, 0, stream>>>(X, ln1g + (size_t)l*E, ln1b + (size_t)l*E, Hb);
      sgemm<false,false><<<dim3(1,T/64,B*H), 256, 0, stream>>>(
          Hb, wq + (size_t)l*H*E*HS, bq + (size_t)l*H*HS, nullptr, Qb,
          T, HS, E, H, (long long)T*E, (long long)E*HS, (long long)HS, (long long)T*HS);
      sgemm<false,false><<<dim3(1,T/64,B*H), 256, 0, stream>>>(
          Hb, wk + (size_t)l*H*E*HS, bk + (size_t)l*H*HS, nullptr, Kb,
          T, HS, E, H, (long long)T*E, (long long)E*HS, (long long)HS, (long long)T*HS);
      sgemm<false,false><<<dim3(1,T/64,B*H), 256, 0, stream>>>(
          Hb, wv + (size_t)l*H*E*HS, bv + (size_t)l*H*HS, nullptr, Vb,
          T, HS, E, H, (long long)T*E, (long long)E*HS, (long long)HS, (long long)T*HS);
      attn_kernel<<<B*H*(T/4), 256, 0, stream>>>(Qb, Kb, Vb, amask, ATT);
      sgemm<false,true><<<dim3(E/64, NTOK/64, 1), 256, 0, stream>>>(
          ATT, wo + (size_t)l*E*E, bo + (size_t)l*E, X, X,
          NTOK, E, E, 1, 0,0,0,0);
      ln_kernel<<<NTOK, 256, 0, stream>>>(X, ln2g + (size_t)l*E, ln2b + (size_t)l*E, Hb);
      sgemm<true,false><<<dim3(FF/64, NTOK/64, 1), 256, 0, stream>>>(
          Hb, w1 + (size_t)l*E*FF, b1 + (size_t)l*FF, nullptr, U,
          NTOK, FF, E, 1, 0,0,0,0);
      sgemm<false,true><<<dim3(E/64, NTOK/64, 1), 256, 0, stream>>>(
          U, w2 + (size_t)l*FF*E, b2 + (size_t)l*E, X, X,
          NTOK, E, FF, 1, 0,0,0,0);
    }
    ln_kernel<<<NTOK, 256, 0, stream>>>(X, lnfg, lnfb, Hb);
    sgemm<false,false><<<dim3((V+63)/64, NTOK/64, 1), 256, 0, stream>>>(
        Hb, wf, bf, nullptr, out, NTOK, V, E, 1, 0,0,0,0);
    loss_row<<<NTOK, 256, 0, stream>>>(out, tgt, PART);
    loss_final<<<1, 256, 0, stream>>>(PART, out + (size_t)NTOK*V);
  }
}